// Round 1
// baseline (622.163 us; speedup 1.0000x reference)
//
#include <hip/hip_runtime.h>
#include <cmath>

#define N_NODES 50000
#define DIM 64
#define E_EDGES 800000
#define CHUNK 782            // ceil(50000 / 64)

// ---------------- score + deg init ----------------
// one wave per node: score[n] = dot(x[n], p) / ||p||; deg[n] = 1.0 (self loop)
__global__ __launch_bounds__(256) void score_kernel(
    const float* __restrict__ x, const float* __restrict__ p,
    float* __restrict__ score, float* __restrict__ deg) {
    int gid = blockIdx.x * blockDim.x + threadIdx.x;
    int n = gid >> 6, lane = gid & 63;
    if (n >= N_NODES) return;
    float pv = p[lane];
    float v = x[n * DIM + lane] * pv;
    float pn = pv * pv;
    for (int off = 32; off > 0; off >>= 1) {
        v  += __shfl_down(v, off);
        pn += __shfl_down(pn, off);
    }
    if (lane == 0) {
        score[n] = v / sqrtf(pn);
        deg[n] = 1.0f;
    }
}

// ---------------- degree scatter ----------------
__global__ __launch_bounds__(256) void deg_kernel(
    const int* __restrict__ ei, const float* __restrict__ ew,
    float* __restrict__ deg) {
    int e = blockIdx.x * blockDim.x + threadIdx.x;
    if (e >= E_EDGES) return;
    atomicAdd(&deg[ei[E_EDGES + e]], ew[e]);
}

// ---------------- top-k phase A: per-block local top-64 ----------------
__global__ __launch_bounds__(256) void topk_a_kernel(
    const float* __restrict__ score,
    float* __restrict__ cand_val, int* __restrict__ cand_idx) {
    __shared__ float sv[CHUNK];
    __shared__ float wv[4];
    __shared__ int   wi[4];
    int t = threadIdx.x;
    int base = blockIdx.x * CHUNK;
    for (int i = t; i < CHUNK; i += 256) {
        int g = base + i;
        sv[i] = (g < N_NODES) ? score[g] : -INFINITY;
    }
    __syncthreads();
    int lane = t & 63, wid = t >> 6;
    for (int iter = 0; iter < 64; iter++) {
        float bv = -INFINITY; int bi = 0x7fffffff;
        for (int i = t; i < CHUNK; i += 256) {
            float v = sv[i];
            int g = base + i;
            if (v > bv || (v == bv && g < bi)) { bv = v; bi = g; }
        }
        for (int off = 32; off > 0; off >>= 1) {
            float ov = __shfl_down(bv, off);
            int   oi = __shfl_down(bi, off);
            if (ov > bv || (ov == bv && oi < bi)) { bv = ov; bi = oi; }
        }
        if (lane == 0) { wv[wid] = bv; wi[wid] = bi; }
        __syncthreads();
        if (t == 0) {
            float fv = wv[0]; int fi = wi[0];
            for (int j = 1; j < 4; j++)
                if (wv[j] > fv || (wv[j] == fv && wi[j] < fi)) { fv = wv[j]; fi = wi[j]; }
            cand_val[blockIdx.x * 64 + iter] = fv;
            cand_idx[blockIdx.x * 64 + iter] = fi;
            sv[fi - base] = -INFINITY;
        }
        __syncthreads();
    }
}

// ---------------- top-k phase B: global top-64 + build x_tilde ----------------
__global__ __launch_bounds__(256) void topk_b_kernel(
    const float* __restrict__ cand_val, const int* __restrict__ cand_idx,
    const float* __restrict__ x, float* __restrict__ x_tilde) {
    __shared__ float sv[4096];
    __shared__ int   si[4096];
    __shared__ float wv[4];
    __shared__ int   wi[4], wslot[4];
    __shared__ int   perm_s[64];
    __shared__ float val_s[64];
    int t = threadIdx.x;
    for (int i = t; i < 4096; i += 256) { sv[i] = cand_val[i]; si[i] = cand_idx[i]; }
    __syncthreads();
    int lane = t & 63, wid = t >> 6;
    for (int iter = 0; iter < 64; iter++) {
        float bv = -INFINITY; int bi = 0x7fffffff; int bs = 0;
        for (int i = t; i < 4096; i += 256) {
            float v = sv[i];
            if (v > bv || (v == bv && si[i] < bi)) { bv = v; bi = si[i]; bs = i; }
        }
        for (int off = 32; off > 0; off >>= 1) {
            float ov = __shfl_down(bv, off);
            int   oi = __shfl_down(bi, off);
            int   os = __shfl_down(bs, off);
            if (ov > bv || (ov == bv && oi < bi)) { bv = ov; bi = oi; bs = os; }
        }
        if (lane == 0) { wv[wid] = bv; wi[wid] = bi; wslot[wid] = bs; }
        __syncthreads();
        if (t == 0) {
            float fv = wv[0]; int fi = wi[0]; int fs = wslot[0];
            for (int j = 1; j < 4; j++)
                if (wv[j] > fv || (wv[j] == fv && wi[j] < fi)) { fv = wv[j]; fi = wi[j]; fs = wslot[j]; }
            perm_s[iter] = fi;
            val_s[iter] = fv;
            sv[fs] = -INFINITY;
        }
        __syncthreads();
    }
    // x_tilde[j][k] = x[perm[j]][k] * tanh(val[j])
    for (int i = t; i < 4096; i += 256) {
        int j = i >> 6, k = i & 63;
        x_tilde[i] = x[perm_s[j] * DIM + k] * tanhf(val_s[j]);
    }
}

// ---------------- GRU step: evolve W ----------------
__global__ __launch_bounds__(64) void gru_kernel(
    const float* __restrict__ xt, const float* __restrict__ initW,
    const float* __restrict__ Wih, const float* __restrict__ Whh,
    const float* __restrict__ bih, const float* __restrict__ bhh,
    float* __restrict__ Wout) {
    __shared__ float xrow[64], hrow[64];
    int i = blockIdx.x, j = threadIdx.x;
    xrow[j] = xt[i * 64 + j];
    hrow[j] = initW[i * 64 + j];
    __syncthreads();
    float gi_r = bih[j], gi_z = bih[j + 64], gi_n = bih[j + 128];
    float gh_r = bhh[j], gh_z = bhh[j + 64], gh_n = bhh[j + 128];
    for (int k = 0; k < 64; k++) {
        float xv = xrow[k], hv = hrow[k];
        gi_r += xv * Wih[j * 64 + k];
        gi_z += xv * Wih[(j + 64) * 64 + k];
        gi_n += xv * Wih[(j + 128) * 64 + k];
        gh_r += hv * Whh[j * 64 + k];
        gh_z += hv * Whh[(j + 64) * 64 + k];
        gh_n += hv * Whh[(j + 128) * 64 + k];
    }
    float r = 1.f / (1.f + expf(-(gi_r + gh_r)));
    float z = 1.f / (1.f + expf(-(gi_z + gh_z)));
    float nn = tanhf(gi_n + r * gh_n);
    Wout[i * 64 + j] = (1.f - z) * nn + z * hrow[j];
}

// ---------------- xw = x @ W ----------------
__global__ __launch_bounds__(256) void xw_kernel(
    const float* __restrict__ x, const float* __restrict__ W,
    float* __restrict__ xw) {
    __shared__ float Wl[64 * 64];
    __shared__ float Xl[64 * 64];
    int t = threadIdx.x;
    int r0 = blockIdx.x * 64;
    for (int i = t; i < 4096; i += 256) Wl[i] = W[i];
    for (int i = t; i < 4096; i += 256) {
        int r = r0 + (i >> 6);
        Xl[i] = (r < N_NODES) ? x[r0 * 64 + i] : 0.f;
    }
    __syncthreads();
    int j = t & 63, ty = t >> 6;     // each thread: 16 rows x 1 col
    float acc[16];
    #pragma unroll
    for (int rr = 0; rr < 16; rr++) acc[rr] = 0.f;
    for (int k = 0; k < 64; k++) {
        float wvv = Wl[k * 64 + j];
        #pragma unroll
        for (int rr = 0; rr < 16; rr++)
            acc[rr] += Xl[(ty * 16 + rr) * 64 + k] * wvv;
    }
    #pragma unroll
    for (int rr = 0; rr < 16; rr++) {
        int r = r0 + ty * 16 + rr;
        if (r < N_NODES) xw[r * 64 + j] = acc[rr];
    }
}

// ---------------- agg init: self-loop contribution + dinv ----------------
__global__ __launch_bounds__(256) void agg_init_kernel(
    const float* __restrict__ deg, const float* __restrict__ xw,
    float* __restrict__ dinv, float* __restrict__ agg) {
    int idx = blockIdx.x * blockDim.x + threadIdx.x;
    if (idx >= N_NODES * DIM) return;
    int n = idx >> 6;
    float d = deg[n];                 // >= 1 (self loop)
    float di = 1.0f / sqrtf(d);
    if ((idx & 63) == 0) dinv[n] = di;
    agg[idx] = di * di * xw[idx];     // self-loop: dinv[n]*1*dinv[n]*xw[n]
}

// ---------------- main edge scatter: wave per edge ----------------
__global__ __launch_bounds__(256) void scatter_kernel(
    const int* __restrict__ ei, const float* __restrict__ ew,
    const float* __restrict__ dinv, const float* __restrict__ xw,
    float* __restrict__ agg) {
    int gid = blockIdx.x * blockDim.x + threadIdx.x;
    int e = gid >> 6, lane = gid & 63;
    if (e >= E_EDGES) return;
    int r = ei[e], c = ei[E_EDGES + e];
    float norm = dinv[r] * ew[e] * dinv[c];
    atomicAdd(&agg[c * DIM + lane], norm * xw[r * DIM + lane]);
}

// ---------------- head: relu + Linear(D,1) ----------------
__global__ __launch_bounds__(256) void head_kernel(
    const float* __restrict__ agg, const float* __restrict__ linW,
    const float* __restrict__ linb, float* __restrict__ out) {
    int gid = blockIdx.x * blockDim.x + threadIdx.x;
    int n = gid >> 6, lane = gid & 63;
    if (n >= N_NODES) return;
    float v = fmaxf(agg[n * DIM + lane], 0.f) * linW[lane];
    for (int off = 32; off > 0; off >>= 1) v += __shfl_down(v, off);
    if (lane == 0) out[n] = v + linb[0];
}

extern "C" void kernel_launch(void* const* d_in, const int* in_sizes, int n_in,
                              void* d_out, int out_size, void* d_ws, size_t ws_size,
                              hipStream_t stream) {
    const float* x     = (const float*)d_in[0];
    const int*   ei    = (const int*)d_in[1];
    const float* ew    = (const float*)d_in[2];
    const float* p     = (const float*)d_in[3];
    const float* initW = (const float*)d_in[4];
    const float* Wih   = (const float*)d_in[5];
    const float* Whh   = (const float*)d_in[6];
    const float* bih   = (const float*)d_in[7];
    const float* bhh   = (const float*)d_in[8];
    const float* linW  = (const float*)d_in[9];
    const float* linb  = (const float*)d_in[10];
    float* out = (float*)d_out;

    float* ws       = (float*)d_ws;
    float* score    = ws;                       // N
    float* deg      = score + N_NODES;          // N
    float* dinv     = deg + N_NODES;            // N
    float* xw       = dinv + N_NODES;           // N*64
    float* agg      = xw + (size_t)N_NODES * DIM;      // N*64
    float* cand_val = agg + (size_t)N_NODES * DIM;     // 4096
    int*   cand_idx = (int*)(cand_val + 4096);  // 4096
    float* x_tilde  = (float*)(cand_idx + 4096);// 4096
    float* W        = x_tilde + 4096;           // 4096

    score_kernel<<<(N_NODES * 64 + 255) / 256, 256, 0, stream>>>(x, p, score, deg);
    deg_kernel<<<(E_EDGES + 255) / 256, 256, 0, stream>>>(ei, ew, deg);
    topk_a_kernel<<<64, 256, 0, stream>>>(score, cand_val, cand_idx);
    topk_b_kernel<<<1, 256, 0, stream>>>(cand_val, cand_idx, x, x_tilde);
    gru_kernel<<<64, 64, 0, stream>>>(x_tilde, initW, Wih, Whh, bih, bhh, W);
    xw_kernel<<<(N_NODES + 63) / 64, 256, 0, stream>>>(x, W, xw);
    agg_init_kernel<<<(N_NODES * DIM + 255) / 256, 256, 0, stream>>>(deg, xw, dinv, agg);
    scatter_kernel<<<((size_t)E_EDGES * 64 + 255) / 256, 256, 0, stream>>>(ei, ew, dinv, xw, agg);
    head_kernel<<<(N_NODES * 64 + 255) / 256, 256, 0, stream>>>(agg, linW, linb, out);
}

// Round 2
// 429.618 us; speedup vs baseline: 1.4482x; 1.4482x over previous
//
#include <hip/hip_runtime.h>
#include <cmath>

#define N_NODES 50000
#define DIM 64
#define E_EDGES 800000
#define CHUNK 782            // ceil(50000 / 64)
#define SCAN_BLOCKS 196      // ceil(50000 / 256)

// ---------------- score + init (deg=1 self-loop, cnt=0, fill=0) ----------------
__global__ __launch_bounds__(256) void score_kernel(
    const float* __restrict__ x, const float* __restrict__ p,
    float* __restrict__ score, float* __restrict__ deg,
    int* __restrict__ cnt, int* __restrict__ fillc) {
    int gid = blockIdx.x * blockDim.x + threadIdx.x;
    int n = gid >> 6, lane = gid & 63;
    if (n >= N_NODES) return;
    float pv = p[lane];
    float v = x[n * DIM + lane] * pv;
    float pn = pv * pv;
    for (int off = 32; off > 0; off >>= 1) {
        v  += __shfl_down(v, off);
        pn += __shfl_down(pn, off);
    }
    if (lane == 0) {
        score[n] = v / sqrtf(pn);
        deg[n] = 1.0f;      // self-loop weight
        cnt[n] = 0;
        fillc[n] = 0;
    }
}

// ---------------- weighted degree + incoming-edge count ----------------
__global__ __launch_bounds__(256) void deg_cnt_kernel(
    const int* __restrict__ ei, const float* __restrict__ ew,
    float* __restrict__ deg, int* __restrict__ cnt) {
    int e = blockIdx.x * blockDim.x + threadIdx.x;
    if (e >= E_EDGES) return;
    int c = ei[E_EDGES + e];
    atomicAdd(&deg[c], ew[e]);
    atomicAdd(&cnt[c], 1);
}

// ---------------- dinv ----------------
__global__ __launch_bounds__(256) void dinv_kernel(
    const float* __restrict__ deg, float* __restrict__ dinv) {
    int n = blockIdx.x * blockDim.x + threadIdx.x;
    if (n >= N_NODES) return;
    dinv[n] = rsqrtf(deg[n]);   // deg >= 1 always (self loop)
}

// ---------------- exclusive scan of cnt (3 kernels) ----------------
__global__ __launch_bounds__(256) void scan1_kernel(
    const int* __restrict__ cnt, int* __restrict__ off, int* __restrict__ bsum) {
    __shared__ int s[256];
    int t = threadIdx.x;
    int g = blockIdx.x * 256 + t;
    int v = (g < N_NODES) ? cnt[g] : 0;
    s[t] = v;
    __syncthreads();
    for (int d = 1; d < 256; d <<= 1) {
        int add = (t >= d) ? s[t - d] : 0;
        __syncthreads();
        s[t] += add;
        __syncthreads();
    }
    if (g < N_NODES) off[g] = s[t] - v;      // exclusive
    if (t == 255) bsum[blockIdx.x] = s[255];
}

__global__ __launch_bounds__(256) void scan2_kernel(
    const int* __restrict__ bsum, int* __restrict__ boff) {
    __shared__ int s[256];
    int t = threadIdx.x;
    int v = (t < SCAN_BLOCKS) ? bsum[t] : 0;
    s[t] = v;
    __syncthreads();
    for (int d = 1; d < 256; d <<= 1) {
        int add = (t >= d) ? s[t - d] : 0;
        __syncthreads();
        s[t] += add;
        __syncthreads();
    }
    boff[t] = s[t] - v;
}

__global__ __launch_bounds__(256) void scan3_kernel(
    int* __restrict__ off, const int* __restrict__ boff) {
    int g = blockIdx.x * 256 + threadIdx.x;
    if (g < N_NODES) off[g] += boff[blockIdx.x];
}

// ---------------- CSR fill: (row, norm) per destination ----------------
__global__ __launch_bounds__(256) void fill_kernel(
    const int* __restrict__ ei, const float* __restrict__ ew,
    const float* __restrict__ dinv, const int* __restrict__ off,
    int* __restrict__ fillc, int* __restrict__ er, float* __restrict__ en) {
    int e = blockIdx.x * blockDim.x + threadIdx.x;
    if (e >= E_EDGES) return;
    int r = ei[e], c = ei[E_EDGES + e];
    int pos = off[c] + atomicAdd(&fillc[c], 1);
    er[pos] = r;
    en[pos] = dinv[r] * ew[e] * dinv[c];
}

// ---------------- top-k phase A: per-block bitonic sort of 1024 ----------------
__global__ __launch_bounds__(256) void topk_a_kernel(
    const float* __restrict__ score,
    float* __restrict__ cand_val, int* __restrict__ cand_idx) {
    __shared__ float sv[1024];
    __shared__ int   si[1024];
    int t = threadIdx.x;
    int base = blockIdx.x * CHUNK;
    for (int i = t; i < 1024; i += 256) {
        int g = base + i;
        bool ok = (i < CHUNK) && (g < N_NODES);
        sv[i] = ok ? score[g] : -INFINITY;
        si[i] = ok ? g : 0x7fffffff;
    }
    __syncthreads();
    for (int k = 2; k <= 1024; k <<= 1) {
        for (int j = k >> 1; j > 0; j >>= 1) {
            for (int i = t; i < 1024; i += 256) {
                int ixj = i ^ j;
                if (ixj > i) {
                    bool up = ((i & k) == 0);     // descending block
                    float v1 = sv[i], v2 = sv[ixj];
                    int   i1 = si[i], i2 = si[ixj];
                    bool first = (v1 > v2) || (v1 == v2 && i1 < i2);
                    if (first != up) {
                        sv[i] = v2; sv[ixj] = v1;
                        si[i] = i2; si[ixj] = i1;
                    }
                }
            }
            __syncthreads();
        }
    }
    if (t < 64) {
        cand_val[blockIdx.x * 64 + t] = sv[t];
        cand_idx[blockIdx.x * 64 + t] = si[t];
    }
}

// ---------------- top-k phase B: bitonic sort of 4096 + build x_tilde ----------------
__global__ __launch_bounds__(1024) void topk_b_kernel(
    const float* __restrict__ cand_val, const int* __restrict__ cand_idx,
    const float* __restrict__ x, float* __restrict__ x_tilde) {
    __shared__ float sv[4096];
    __shared__ int   si[4096];
    int t = threadIdx.x;
    for (int i = t; i < 4096; i += 1024) { sv[i] = cand_val[i]; si[i] = cand_idx[i]; }
    __syncthreads();
    for (int k = 2; k <= 4096; k <<= 1) {
        for (int j = k >> 1; j > 0; j >>= 1) {
            for (int i = t; i < 4096; i += 1024) {
                int ixj = i ^ j;
                if (ixj > i) {
                    bool up = ((i & k) == 0);
                    float v1 = sv[i], v2 = sv[ixj];
                    int   i1 = si[i], i2 = si[ixj];
                    bool first = (v1 > v2) || (v1 == v2 && i1 < i2);
                    if (first != up) {
                        sv[i] = v2; sv[ixj] = v1;
                        si[i] = i2; si[ixj] = i1;
                    }
                }
            }
            __syncthreads();
        }
    }
    // x_tilde[j][k] = x[perm[j]][k] * tanh(val[j]), top-64 now at sv/si[0..63]
    for (int i = t; i < 4096; i += 1024) {
        int j = i >> 6, kk = i & 63;
        x_tilde[i] = x[si[j] * DIM + kk] * tanhf(sv[j]);
    }
}

// ---------------- GRU step: evolve W ----------------
__global__ __launch_bounds__(64) void gru_kernel(
    const float* __restrict__ xt, const float* __restrict__ initW,
    const float* __restrict__ Wih, const float* __restrict__ Whh,
    const float* __restrict__ bih, const float* __restrict__ bhh,
    float* __restrict__ Wout) {
    __shared__ float xrow[64], hrow[64];
    int i = blockIdx.x, j = threadIdx.x;
    xrow[j] = xt[i * 64 + j];
    hrow[j] = initW[i * 64 + j];
    __syncthreads();
    float gi_r = bih[j], gi_z = bih[j + 64], gi_n = bih[j + 128];
    float gh_r = bhh[j], gh_z = bhh[j + 64], gh_n = bhh[j + 128];
    for (int k = 0; k < 64; k++) {
        float xv = xrow[k], hv = hrow[k];
        gi_r += xv * Wih[j * 64 + k];
        gi_z += xv * Wih[(j + 64) * 64 + k];
        gi_n += xv * Wih[(j + 128) * 64 + k];
        gh_r += hv * Whh[j * 64 + k];
        gh_z += hv * Whh[(j + 64) * 64 + k];
        gh_n += hv * Whh[(j + 128) * 64 + k];
    }
    float r = 1.f / (1.f + expf(-(gi_r + gh_r)));
    float z = 1.f / (1.f + expf(-(gi_z + gh_z)));
    float nn = tanhf(gi_n + r * gh_n);
    Wout[i * 64 + j] = (1.f - z) * nn + z * hrow[j];
}

// ---------------- xw = x @ W ----------------
__global__ __launch_bounds__(256) void xw_kernel(
    const float* __restrict__ x, const float* __restrict__ W,
    float* __restrict__ xw) {
    __shared__ float Wl[64 * 64];
    __shared__ float Xl[64 * 64];
    int t = threadIdx.x;
    int r0 = blockIdx.x * 64;
    for (int i = t; i < 4096; i += 256) Wl[i] = W[i];
    for (int i = t; i < 4096; i += 256) {
        int r = r0 + (i >> 6);
        Xl[i] = (r < N_NODES) ? x[r0 * 64 + i] : 0.f;
    }
    __syncthreads();
    int j = t & 63, ty = t >> 6;     // each thread: 16 rows x 1 col
    float acc[16];
    #pragma unroll
    for (int rr = 0; rr < 16; rr++) acc[rr] = 0.f;
    for (int k = 0; k < 64; k++) {
        float wvv = Wl[k * 64 + j];
        #pragma unroll
        for (int rr = 0; rr < 16; rr++)
            acc[rr] += Xl[(ty * 16 + rr) * 64 + k] * wvv;
    }
    #pragma unroll
    for (int rr = 0; rr < 16; rr++) {
        int r = r0 + ty * 16 + rr;
        if (r < N_NODES) xw[r * 64 + j] = acc[rr];
    }
}

// ---------------- gather + fused head: wave per destination node ----------------
__global__ __launch_bounds__(256) void gather_head_kernel(
    const int* __restrict__ off, const int* __restrict__ cnt,
    const int* __restrict__ er, const float* __restrict__ en,
    const float* __restrict__ dinv, const float* __restrict__ xw,
    const float* __restrict__ linW, const float* __restrict__ linb,
    float* __restrict__ out) {
    int gid = blockIdx.x * blockDim.x + threadIdx.x;
    int n = gid >> 6, lane = gid & 63;
    if (n >= N_NODES) return;
    float di = dinv[n];
    float acc = di * di * xw[n * DIM + lane];    // self-loop term
    int s = off[n], e = s + cnt[n];
    for (int pos = s; pos < e; pos++) {
        int r = er[pos];
        float nm = en[pos];
        acc += nm * xw[r * DIM + lane];
    }
    float v = fmaxf(acc, 0.f) * linW[lane];
    for (int o = 32; o > 0; o >>= 1) v += __shfl_down(v, o);
    if (lane == 0) out[n] = v + linb[0];
}

extern "C" void kernel_launch(void* const* d_in, const int* in_sizes, int n_in,
                              void* d_out, int out_size, void* d_ws, size_t ws_size,
                              hipStream_t stream) {
    const float* x     = (const float*)d_in[0];
    const int*   ei    = (const int*)d_in[1];
    const float* ew    = (const float*)d_in[2];
    const float* p     = (const float*)d_in[3];
    const float* initW = (const float*)d_in[4];
    const float* Wih   = (const float*)d_in[5];
    const float* Whh   = (const float*)d_in[6];
    const float* bih   = (const float*)d_in[7];
    const float* bhh   = (const float*)d_in[8];
    const float* linW  = (const float*)d_in[9];
    const float* linb  = (const float*)d_in[10];
    float* out = (float*)d_out;

    char* w = (char*)d_ws;
    float* score    = (float*)w;                w += sizeof(float) * N_NODES;
    float* deg      = (float*)w;                w += sizeof(float) * N_NODES;
    float* dinv     = (float*)w;                w += sizeof(float) * N_NODES;
    int*   cnt      = (int*)w;                  w += sizeof(int) * N_NODES;
    int*   fillc    = (int*)w;                  w += sizeof(int) * N_NODES;
    int*   off      = (int*)w;                  w += sizeof(int) * N_NODES;
    float* xw       = (float*)w;                w += sizeof(float) * (size_t)N_NODES * DIM;
    int*   er       = (int*)w;                  w += sizeof(int) * (size_t)E_EDGES;
    float* en       = (float*)w;                w += sizeof(float) * (size_t)E_EDGES;
    float* cand_val = (float*)w;                w += sizeof(float) * 4096;
    int*   cand_idx = (int*)w;                  w += sizeof(int) * 4096;
    float* x_tilde  = (float*)w;                w += sizeof(float) * 4096;
    float* W        = (float*)w;                w += sizeof(float) * 4096;
    int*   bsum     = (int*)w;                  w += sizeof(int) * 256;
    int*   boff     = (int*)w;                  w += sizeof(int) * 256;

    // scores + init
    score_kernel<<<(N_NODES * 64 + 255) / 256, 256, 0, stream>>>(x, p, score, deg, cnt, fillc);
    // degree + count
    deg_cnt_kernel<<<(E_EDGES + 255) / 256, 256, 0, stream>>>(ei, ew, deg, cnt);
    // top-k + GRU + xw (independent of CSR build; sequential on stream is fine)
    topk_a_kernel<<<64, 256, 0, stream>>>(score, cand_val, cand_idx);
    topk_b_kernel<<<1, 1024, 0, stream>>>(cand_val, cand_idx, x, x_tilde);
    gru_kernel<<<64, 64, 0, stream>>>(x_tilde, initW, Wih, Whh, bih, bhh, W);
    xw_kernel<<<(N_NODES + 63) / 64, 256, 0, stream>>>(x, W, xw);
    // CSR build
    dinv_kernel<<<(N_NODES + 255) / 256, 256, 0, stream>>>(deg, dinv);
    scan1_kernel<<<SCAN_BLOCKS, 256, 0, stream>>>(cnt, off, bsum);
    scan2_kernel<<<1, 256, 0, stream>>>(bsum, boff);
    scan3_kernel<<<SCAN_BLOCKS, 256, 0, stream>>>(off, boff);
    fill_kernel<<<(E_EDGES + 255) / 256, 256, 0, stream>>>(ei, ew, dinv, off, fillc, er, en);
    // gather + fused relu/linear head
    gather_head_kernel<<<(N_NODES * 64 + 255) / 256, 256, 0, stream>>>(
        off, cnt, er, en, dinv, xw, linW, linb, out);
}

// Round 3
// 319.833 us; speedup vs baseline: 1.9453x; 1.3433x over previous
//
#include <hip/hip_runtime.h>
#include <cmath>

#define N_NODES 50000
#define DIM 64
#define E_EDGES 800000
#define CHUNK 782            // ceil(50000 / 64)
#define SCAN_BLOCKS 196      // ceil(50000 / 256)
#define FIX 16777216.0f      // 2^24 fixed-point scale for deg
#define DEG_MASK 0xFFFFFFFFFFull   // low 40 bits

// ---------------- score + init (packed deg/cnt, fillc) ----------------
// packed[n]: bits 0..39 = deg * 2^24 (self-loop preloaded), bits 40.. = in-count
__global__ __launch_bounds__(256) void score_kernel(
    const float* __restrict__ x, const float* __restrict__ p,
    float* __restrict__ score, unsigned long long* __restrict__ packed,
    int* __restrict__ fillc) {
    int gid = blockIdx.x * blockDim.x + threadIdx.x;
    int n = gid >> 6, lane = gid & 63;
    if (n >= N_NODES) return;
    float pv = p[lane];
    float v = x[n * DIM + lane] * pv;
    float pn = pv * pv;
    for (int off = 32; off > 0; off >>= 1) {
        v  += __shfl_down(v, off);
        pn += __shfl_down(pn, off);
    }
    if (lane == 0) {
        score[n] = v / sqrtf(pn);
        packed[n] = (1ull << 24);   // deg = 1.0 (self loop), cnt = 0
        fillc[n] = 0;
    }
}

// ---------------- weighted degree + incoming count: ONE u64 atomic/edge ----------------
__global__ __launch_bounds__(256) void deg_cnt_kernel(
    const int* __restrict__ ei, const float* __restrict__ ew,
    unsigned long long* __restrict__ packed) {
    int e = blockIdx.x * blockDim.x + threadIdx.x;
    if (e >= E_EDGES) return;
    int c = ei[E_EDGES + e];
    unsigned long long q = (unsigned long long)(ew[e] * FIX);
    atomicAdd(&packed[c], (1ull << 40) | q);
}

// ---------------- scan1: block-exclusive scan of cnt; also dinv ----------------
__global__ __launch_bounds__(256) void scan1_kernel(
    const unsigned long long* __restrict__ packed,
    int* __restrict__ off, int* __restrict__ bsum, float* __restrict__ dinv) {
    __shared__ int s[256];
    int t = threadIdx.x;
    int g = blockIdx.x * 256 + t;
    unsigned long long pk = (g < N_NODES) ? packed[g] : 0ull;
    int v = (int)(pk >> 40);
    if (g < N_NODES)
        dinv[g] = rsqrtf((float)(pk & DEG_MASK) * (1.0f / FIX));
    s[t] = v;
    __syncthreads();
    for (int d = 1; d < 256; d <<= 1) {
        int add = (t >= d) ? s[t - d] : 0;
        __syncthreads();
        s[t] += add;
        __syncthreads();
    }
    if (g < N_NODES) off[g] = s[t] - v;      // exclusive within block
    if (t == 255) bsum[blockIdx.x] = s[255];
}

__global__ __launch_bounds__(256) void scan2_kernel(
    const int* __restrict__ bsum, int* __restrict__ boff) {
    __shared__ int s[256];
    int t = threadIdx.x;
    int v = (t < SCAN_BLOCKS) ? bsum[t] : 0;
    s[t] = v;
    __syncthreads();
    for (int d = 1; d < 256; d <<= 1) {
        int add = (t >= d) ? s[t - d] : 0;
        __syncthreads();
        s[t] += add;
        __syncthreads();
    }
    boff[t] = s[t] - v;
}

// ---------------- CSR fill: packed (row, norm) 8B record per edge ----------------
__global__ __launch_bounds__(256) void fill_kernel(
    const int* __restrict__ ei, const float* __restrict__ ew,
    const float* __restrict__ dinv, const int* __restrict__ off,
    const int* __restrict__ boff, int* __restrict__ fillc,
    float2* __restrict__ ren) {
    int e = blockIdx.x * blockDim.x + threadIdx.x;
    if (e >= E_EDGES) return;
    int r = ei[e], c = ei[E_EDGES + e];
    int pos = off[c] + boff[c >> 8] + atomicAdd(&fillc[c], 1);
    ren[pos] = make_float2(__int_as_float(r), dinv[r] * ew[e] * dinv[c]);
}

// ---------------- top-k phase A: bitonic sort 1024, alternating run direction ----------------
__global__ __launch_bounds__(256) void topk_a_kernel(
    const float* __restrict__ score,
    float* __restrict__ cand_val, int* __restrict__ cand_idx) {
    __shared__ float sv[1024];
    __shared__ int   si[1024];
    int t = threadIdx.x;
    int base = blockIdx.x * CHUNK;
    for (int i = t; i < 1024; i += 256) {
        int g = base + i;
        bool ok = (i < CHUNK) && (g < N_NODES);
        sv[i] = ok ? score[g] : -INFINITY;
        si[i] = ok ? g : 0x7fffffff;
    }
    __syncthreads();
    for (int k = 2; k <= 1024; k <<= 1) {
        for (int j = k >> 1; j > 0; j >>= 1) {
            for (int i = t; i < 1024; i += 256) {
                int ixj = i ^ j;
                if (ixj > i) {
                    bool up = ((i & k) == 0);     // descending block
                    float v1 = sv[i], v2 = sv[ixj];
                    int   i1 = si[i], i2 = si[ixj];
                    bool first = (v1 > v2) || (v1 == v2 && i1 < i2);
                    if (first != up) {
                        sv[i] = v2; sv[ixj] = v1;
                        si[i] = i2; si[ixj] = i1;
                    }
                }
            }
            __syncthreads();
        }
    }
    // even blocks: descending run; odd blocks: reversed (ascending) run,
    // so phase B can start its bitonic merge at k=128.
    if (t < 64) {
        int src = (blockIdx.x & 1) ? (63 - t) : t;
        cand_val[blockIdx.x * 64 + t] = sv[src];
        cand_idx[blockIdx.x * 64 + t] = si[src];
    }
}

// ---------------- top-k phase B: bitonic merge from k=128 + build x_tilde ----------------
__global__ __launch_bounds__(1024) void topk_b_kernel(
    const float* __restrict__ cand_val, const int* __restrict__ cand_idx,
    const float* __restrict__ x, float* __restrict__ x_tilde) {
    __shared__ float sv[4096];
    __shared__ int   si[4096];
    int t = threadIdx.x;
    for (int i = t; i < 4096; i += 1024) { sv[i] = cand_val[i]; si[i] = cand_idx[i]; }
    __syncthreads();
    for (int k = 128; k <= 4096; k <<= 1) {
        for (int j = k >> 1; j > 0; j >>= 1) {
            for (int i = t; i < 4096; i += 1024) {
                int ixj = i ^ j;
                if (ixj > i) {
                    bool up = ((i & k) == 0);
                    float v1 = sv[i], v2 = sv[ixj];
                    int   i1 = si[i], i2 = si[ixj];
                    bool first = (v1 > v2) || (v1 == v2 && i1 < i2);
                    if (first != up) {
                        sv[i] = v2; sv[ixj] = v1;
                        si[i] = i2; si[ixj] = i1;
                    }
                }
            }
            __syncthreads();
        }
    }
    for (int i = t; i < 4096; i += 1024) {
        int j = i >> 6, kk = i & 63;
        x_tilde[i] = x[si[j] * DIM + kk] * tanhf(sv[j]);
    }
}

// ---------------- GRU step: evolve W ----------------
__global__ __launch_bounds__(64) void gru_kernel(
    const float* __restrict__ xt, const float* __restrict__ initW,
    const float* __restrict__ Wih, const float* __restrict__ Whh,
    const float* __restrict__ bih, const float* __restrict__ bhh,
    float* __restrict__ Wout) {
    __shared__ float xrow[64], hrow[64];
    int i = blockIdx.x, j = threadIdx.x;
    xrow[j] = xt[i * 64 + j];
    hrow[j] = initW[i * 64 + j];
    __syncthreads();
    float gi_r = bih[j], gi_z = bih[j + 64], gi_n = bih[j + 128];
    float gh_r = bhh[j], gh_z = bhh[j + 64], gh_n = bhh[j + 128];
    for (int k = 0; k < 64; k++) {
        float xv = xrow[k], hv = hrow[k];
        gi_r += xv * Wih[j * 64 + k];
        gi_z += xv * Wih[(j + 64) * 64 + k];
        gi_n += xv * Wih[(j + 128) * 64 + k];
        gh_r += hv * Whh[j * 64 + k];
        gh_z += hv * Whh[(j + 64) * 64 + k];
        gh_n += hv * Whh[(j + 128) * 64 + k];
    }
    float r = 1.f / (1.f + expf(-(gi_r + gh_r)));
    float z = 1.f / (1.f + expf(-(gi_z + gh_z)));
    float nn = tanhf(gi_n + r * gh_n);
    Wout[i * 64 + j] = (1.f - z) * nn + z * hrow[j];
}

// ---------------- xw = x @ W ----------------
__global__ __launch_bounds__(256) void xw_kernel(
    const float* __restrict__ x, const float* __restrict__ W,
    float* __restrict__ xw) {
    __shared__ float Wl[64 * 64];
    __shared__ float Xl[64 * 64];
    int t = threadIdx.x;
    int r0 = blockIdx.x * 64;
    for (int i = t; i < 4096; i += 256) Wl[i] = W[i];
    for (int i = t; i < 4096; i += 256) {
        int r = r0 + (i >> 6);
        Xl[i] = (r < N_NODES) ? x[r0 * 64 + i] : 0.f;
    }
    __syncthreads();
    int j = t & 63, ty = t >> 6;
    float acc[16];
    #pragma unroll
    for (int rr = 0; rr < 16; rr++) acc[rr] = 0.f;
    for (int k = 0; k < 64; k++) {
        float wvv = Wl[k * 64 + j];
        #pragma unroll
        for (int rr = 0; rr < 16; rr++)
            acc[rr] += Xl[(ty * 16 + rr) * 64 + k] * wvv;
    }
    #pragma unroll
    for (int rr = 0; rr < 16; rr++) {
        int r = r0 + ty * 16 + rr;
        if (r < N_NODES) xw[r * DIM + j] = acc[rr];
    }
}

// ---------------- gather + fused head: wave per node, 4-edge MLP ----------------
__global__ __launch_bounds__(256) void gather_head_kernel(
    const int* __restrict__ off, const int* __restrict__ boff,
    const float2* __restrict__ ren, const float* __restrict__ dinv,
    const float* __restrict__ xw, const float* __restrict__ linW,
    const float* __restrict__ linb, float* __restrict__ out) {
    int gid = blockIdx.x * blockDim.x + threadIdx.x;
    int n = gid >> 6, lane = gid & 63;
    if (n >= N_NODES) return;
    float di = dinv[n];
    float acc = di * di * xw[n * DIM + lane];    // self-loop term
    int s = off[n] + boff[n >> 8];
    int e = (n == N_NODES - 1) ? E_EDGES : off[n + 1] + boff[(n + 1) >> 8];
    for (int base = s; base < e; base += 64) {
        int m = min(64, e - base);
        // lanes cooperatively load up to 64 edge records, coalesced
        int rv = 0; float wv = 0.f;
        if (base + lane < e) {
            float2 pk = ren[base + lane];
            rv = __float_as_int(pk.x);
            wv = pk.y;
        }
        int j = 0;
        for (; j + 4 <= m; j += 4) {
            int r0 = __shfl(rv, j),     r1 = __shfl(rv, j + 1);
            int r2 = __shfl(rv, j + 2), r3 = __shfl(rv, j + 3);
            float w0 = __shfl(wv, j),     w1 = __shfl(wv, j + 1);
            float w2 = __shfl(wv, j + 2), w3 = __shfl(wv, j + 3);
            float v0 = xw[r0 * DIM + lane];
            float v1 = xw[r1 * DIM + lane];
            float v2 = xw[r2 * DIM + lane];
            float v3 = xw[r3 * DIM + lane];
            acc += w0 * v0;
            acc += w1 * v1;
            acc += w2 * v2;
            acc += w3 * v3;
        }
        for (; j < m; j++) {
            int r = __shfl(rv, j);
            float ww = __shfl(wv, j);
            acc += ww * xw[r * DIM + lane];
        }
    }
    float v = fmaxf(acc, 0.f) * linW[lane];
    for (int o = 32; o > 0; o >>= 1) v += __shfl_down(v, o);
    if (lane == 0) out[n] = v + linb[0];
}

extern "C" void kernel_launch(void* const* d_in, const int* in_sizes, int n_in,
                              void* d_out, int out_size, void* d_ws, size_t ws_size,
                              hipStream_t stream) {
    const float* x     = (const float*)d_in[0];
    const int*   ei    = (const int*)d_in[1];
    const float* ew    = (const float*)d_in[2];
    const float* p     = (const float*)d_in[3];
    const float* initW = (const float*)d_in[4];
    const float* Wih   = (const float*)d_in[5];
    const float* Whh   = (const float*)d_in[6];
    const float* bih   = (const float*)d_in[7];
    const float* bhh   = (const float*)d_in[8];
    const float* linW  = (const float*)d_in[9];
    const float* linb  = (const float*)d_in[10];
    float* out = (float*)d_out;

    // 8-byte-aligned allocations first
    char* w = (char*)d_ws;
    unsigned long long* packed = (unsigned long long*)w; w += 8ull * N_NODES;
    float2* ren    = (float2*)w;   w += 8ull * E_EDGES;
    float* score   = (float*)w;    w += 4ull * N_NODES;
    float* dinv    = (float*)w;    w += 4ull * N_NODES;
    int*   fillc   = (int*)w;      w += 4ull * N_NODES;
    int*   off     = (int*)w;      w += 4ull * N_NODES;
    float* xw      = (float*)w;    w += 4ull * (size_t)N_NODES * DIM;
    float* cand_val= (float*)w;    w += 4ull * 4096;
    int*   cand_idx= (int*)w;      w += 4ull * 4096;
    float* x_tilde = (float*)w;    w += 4ull * 4096;
    float* W       = (float*)w;    w += 4ull * 4096;
    int*   bsum    = (int*)w;      w += 4ull * 256;
    int*   boff    = (int*)w;      w += 4ull * 256;

    score_kernel<<<(N_NODES * 64 + 255) / 256, 256, 0, stream>>>(x, p, score, packed, fillc);
    deg_cnt_kernel<<<(E_EDGES + 255) / 256, 256, 0, stream>>>(ei, ew, packed);
    topk_a_kernel<<<64, 256, 0, stream>>>(score, cand_val, cand_idx);
    topk_b_kernel<<<1, 1024, 0, stream>>>(cand_val, cand_idx, x, x_tilde);
    gru_kernel<<<64, 64, 0, stream>>>(x_tilde, initW, Wih, Whh, bih, bhh, W);
    xw_kernel<<<(N_NODES + 63) / 64, 256, 0, stream>>>(x, W, xw);
    scan1_kernel<<<SCAN_BLOCKS, 256, 0, stream>>>(packed, off, bsum, dinv);
    scan2_kernel<<<1, 256, 0, stream>>>(bsum, boff);
    fill_kernel<<<(E_EDGES + 255) / 256, 256, 0, stream>>>(ei, ew, dinv, off, boff, fillc, ren);
    gather_head_kernel<<<(N_NODES * 64 + 255) / 256, 256, 0, stream>>>(
        off, boff, ren, dinv, xw, linW, linb, out);
}